// Round 1
// baseline (409.241 us; speedup 1.0000x reference)
//
#include <hip/hip_runtime.h>
#include <math.h>

#define D 128
#define DP 132          // padded LDS leading dim (floats): 132%32=4 -> bank-rotating, 16B-aligned rows
#define GRAPHS 64

// ---------------------------------------------------------------------------
// K1: partial Gram matrices. Gram[g] = X_g^T X_g, X_g = feats rows of graph g.
// grid = GRAPHS*KS blocks, 256 threads. Each block: chunk of L/KS rows,
// full 128x128 output, 8x8 micro-tile per thread (16x16 thread grid).
// ---------------------------------------------------------------------------
__global__ __launch_bounds__(256) void gram_partial_kernel(
    const float* __restrict__ feats, float* __restrict__ partial,
    int L, int KS) {
  const int g = blockIdx.x / KS;
  const int s = blockIdx.x - g * KS;
  const int chunk = L / KS;
  const float* __restrict__ X = feats + ((size_t)g * L + (size_t)s * chunk) * D;

  __shared__ float sX[16][DP];
  const int tid = threadIdx.x;
  const int tx = tid & 15;
  const int ty = tid >> 4;

  float acc[8][8];
#pragma unroll
  for (int i = 0; i < 8; ++i)
#pragma unroll
    for (int j = 0; j < 8; ++j) acc[i][j] = 0.f;

  for (int k0 = 0; k0 < chunk; k0 += 16) {
    __syncthreads();
#pragma unroll
    for (int v = 0; v < 2; ++v) {
      int idx = tid + v * 256;            // 512 float4 slots (16 rows x 32)
      int row = idx >> 5;
      int c4 = idx & 31;
      float4 val = *(const float4*)(X + (size_t)(k0 + row) * D + c4 * 4);
      *(float4*)(&sX[row][c4 * 4]) = val;
    }
    __syncthreads();
#pragma unroll
    for (int k = 0; k < 16; ++k) {
      float a[8], b[8];
      *(float4*)&a[0] = *(float4*)&sX[k][ty * 8];
      *(float4*)&a[4] = *(float4*)&sX[k][ty * 8 + 4];
      *(float4*)&b[0] = *(float4*)&sX[k][tx * 8];
      *(float4*)&b[4] = *(float4*)&sX[k][tx * 8 + 4];
#pragma unroll
      for (int i = 0; i < 8; ++i)
#pragma unroll
        for (int j = 0; j < 8; ++j) acc[i][j] += a[i] * b[j];
    }
  }
  float* P = partial + (size_t)blockIdx.x * (D * D);
#pragma unroll
  for (int i = 0; i < 8; ++i) {
    int row = ty * 8 + i;
#pragma unroll
    for (int j = 0; j < 8; j += 4) {
      *(float4*)(P + (size_t)row * D + tx * 8 + j) =
          make_float4(acc[i][j], acc[i][j + 1], acc[i][j + 2], acc[i][j + 3]);
    }
  }
}

// ---------------------------------------------------------------------------
// K2: reduce KS partials -> Gram[GRAPHS][128][128]
// grid = GRAPHS*D*D/256 blocks exactly.
// ---------------------------------------------------------------------------
__global__ __launch_bounds__(256) void gram_reduce_kernel(
    const float* __restrict__ partial, float* __restrict__ gram, int KS) {
  int idx = blockIdx.x * 256 + threadIdx.x;
  int g = idx / (D * D);
  int e = idx - g * (D * D);
  const float* P = partial + ((size_t)g * KS) * (D * D) + e;
  float ssum = 0.f;
  for (int k = 0; k < KS; ++k) ssum += P[(size_t)k * (D * D)];
  gram[idx] = ssum;
}

// ---------------------------------------------------------------------------
// K3: fused main. One block = 32 rows of one graph gi.
//   phase 1: V2 = A * Gram[gi^1]           (A staged in LDS, Gram streamed)
//   phase 2: num/n1s/n2s = (A*V2, A*A, V2*V2) * W2^T  (W2^T squared, streamed)
//   epilogue: out = num / max(sqrt(n1s*n2s), 1e-8)
// Thread micro-tile: 4 rows x 4 cols (cols 4*cg.., rows 4*rg..).
// ---------------------------------------------------------------------------
__global__ __launch_bounds__(256) void fused_kernel(
    const float* __restrict__ feats, const float* __restrict__ w,
    const float* __restrict__ gram, float* __restrict__ out, int L) {
  const int tiles = L / 32;
  const int gi = blockIdx.x / tiles;
  const int row0 = (blockIdx.x - gi * tiles) * 32;
  const float* __restrict__ A = feats + ((size_t)gi * L + row0) * D;
  const float* __restrict__ M = gram + (size_t)(gi ^ 1) * (D * D);
  float* __restrict__ O = out + ((size_t)gi * L + row0) * D;

  __shared__ float sA[32][DP];
  __shared__ float sV[32][DP];
  __shared__ float sM[32][DP];

  const int tid = threadIdx.x;
  const int cg = tid & 31;   // cols 4*cg .. 4*cg+3
  const int rg = tid >> 5;   // rows 4*rg .. 4*rg+3

  // stage A tile: 32 x 128 floats = 1024 float4, 4 per thread
#pragma unroll
  for (int v = 0; v < 4; ++v) {
    int idx = tid + v * 256;
    int r = idx >> 5;
    int c4 = idx & 31;
    *(float4*)&sA[r][c4 * 4] = *(const float4*)(A + (size_t)r * D + c4 * 4);
  }

  float4 acc[4];
#pragma unroll
  for (int i = 0; i < 4; ++i) acc[i] = make_float4(0.f, 0.f, 0.f, 0.f);

  // ---- phase 1: V2 = A * Gram ----
  for (int kc = 0; kc < 4; ++kc) {
    __syncthreads();
#pragma unroll
    for (int v = 0; v < 4; ++v) {
      int idx = tid + v * 256;
      int r = idx >> 5;
      int c4 = idx & 31;
      *(float4*)&sM[r][c4 * 4] =
          *(const float4*)(M + (size_t)(kc * 32 + r) * D + c4 * 4);
    }
    __syncthreads();
#pragma unroll
    for (int k4 = 0; k4 < 32; k4 += 4) {
      float4 av[4];
#pragma unroll
      for (int i = 0; i < 4; ++i)
        av[i] = *(float4*)&sA[rg * 4 + i][kc * 32 + k4];
#pragma unroll
      for (int kk = 0; kk < 4; ++kk) {
        float4 m = *(float4*)&sM[k4 + kk][cg * 4];
#pragma unroll
        for (int i = 0; i < 4; ++i) {
          float a = ((const float*)&av[i])[kk];
          acc[i].x += a * m.x;
          acc[i].y += a * m.y;
          acc[i].z += a * m.z;
          acc[i].w += a * m.w;
        }
      }
    }
  }
  // park V2 in LDS (own micro-tile region; visibility via next barrier)
#pragma unroll
  for (int i = 0; i < 4; ++i) *(float4*)&sV[rg * 4 + i][cg * 4] = acc[i];

  float4 an[4], a1[4], a2[4];
#pragma unroll
  for (int i = 0; i < 4; ++i) {
    an[i] = make_float4(0.f, 0.f, 0.f, 0.f);
    a1[i] = make_float4(0.f, 0.f, 0.f, 0.f);
    a2[i] = make_float4(0.f, 0.f, 0.f, 0.f);
  }

  // ---- phase 2: three GEMMs against W2^T (squared weights, transposed) ----
  for (int dc = 0; dc < 4; ++dc) {
    __syncthreads();
    // sM[dd][p] = w[p][dc*32+dd]^2  (coalesced read along d, scatter store)
#pragma unroll
    for (int v = 0; v < 4; ++v) {
      int idx = tid + v * 256;        // 1024 float4 over 128 p x 8 col4
      int p = idx >> 3;
      int c4 = idx & 7;
      float4 t = *(const float4*)(w + (size_t)p * D + dc * 32 + c4 * 4);
      sM[c4 * 4 + 0][p] = t.x * t.x;
      sM[c4 * 4 + 1][p] = t.y * t.y;
      sM[c4 * 4 + 2][p] = t.z * t.z;
      sM[c4 * 4 + 3][p] = t.w * t.w;
    }
    __syncthreads();
#pragma unroll
    for (int d4 = 0; d4 < 32; d4 += 4) {
      float4 av[4], vv[4];
#pragma unroll
      for (int i = 0; i < 4; ++i) {
        av[i] = *(float4*)&sA[rg * 4 + i][dc * 32 + d4];
        vv[i] = *(float4*)&sV[rg * 4 + i][dc * 32 + d4];
      }
#pragma unroll
      for (int kk = 0; kk < 4; ++kk) {
        float4 wt = *(float4*)&sM[d4 + kk][cg * 4];
#pragma unroll
        for (int i = 0; i < 4; ++i) {
          float a = ((const float*)&av[i])[kk];
          float vvv = ((const float*)&vv[i])[kk];
          float pa = a * vvv;
          float pb = a * a;
          float pc = vvv * vvv;
          an[i].x += pa * wt.x; an[i].y += pa * wt.y;
          an[i].z += pa * wt.z; an[i].w += pa * wt.w;
          a1[i].x += pb * wt.x; a1[i].y += pb * wt.y;
          a1[i].z += pb * wt.z; a1[i].w += pb * wt.w;
          a2[i].x += pc * wt.x; a2[i].y += pc * wt.y;
          a2[i].z += pc * wt.z; a2[i].w += pc * wt.w;
        }
      }
    }
  }

  // ---- epilogue ----
#pragma unroll
  for (int i = 0; i < 4; ++i) {
    float4 res;
    res.x = an[i].x / fmaxf(sqrtf(a1[i].x * a2[i].x), 1e-8f);
    res.y = an[i].y / fmaxf(sqrtf(a1[i].y * a2[i].y), 1e-8f);
    res.z = an[i].z / fmaxf(sqrtf(a1[i].z * a2[i].z), 1e-8f);
    res.w = an[i].w / fmaxf(sqrtf(a1[i].w * a2[i].w), 1e-8f);
    *(float4*)(O + (size_t)(rg * 4 + i) * D + cg * 4) = res;
  }
}

extern "C" void kernel_launch(void* const* d_in, const int* in_sizes, int n_in,
                              void* d_out, int out_size, void* d_ws, size_t ws_size,
                              hipStream_t stream) {
  const float* feats = (const float*)d_in[0];
  const float* w = (const float*)d_in[1];
  float* out = (float*)d_out;
  const int L = (in_sizes[0] / D) / GRAPHS;   // 2048 for the bench shape

  const size_t gramBytes = (size_t)GRAPHS * D * D * sizeof(float);  // 4 MiB
  int KS = 8;
  while (KS > 1 && (size_t)(KS + 1) * gramBytes > ws_size) KS >>= 1;

  float* partial = (float*)d_ws;
  float* gramBuf = (float*)((char*)d_ws + (size_t)KS * gramBytes);

  hipLaunchKernelGGL(gram_partial_kernel, dim3(GRAPHS * KS), dim3(256), 0, stream,
                     feats, partial, L, KS);
  hipLaunchKernelGGL(gram_reduce_kernel, dim3(GRAPHS * D * D / 256), dim3(256), 0,
                     stream, partial, gramBuf, KS);
  hipLaunchKernelGGL(fused_kernel, dim3(GRAPHS * (L / 32)), dim3(256), 0, stream,
                     feats, w, gramBuf, out, L);
}

// Round 3
// 166.591 us; speedup vs baseline: 2.4566x; 2.4566x over previous
//
#include <hip/hip_runtime.h>
#include <math.h>

#define D 128
#define GRAPHS 64

typedef __attribute__((ext_vector_type(8))) short bf16x8;
typedef __attribute__((ext_vector_type(4))) float f32x4;

__device__ __forceinline__ unsigned short f2bf(float f) {   // RNE
  union { float f; unsigned u; } v; v.f = f;
  unsigned r = v.u + 0x7fffu + ((v.u >> 16) & 1u);
  return (unsigned short)(r >> 16);
}
__device__ __forceinline__ float bf2f(unsigned short h) {
  union { unsigned u; float f; } v; v.u = ((unsigned)h) << 16;
  return v.f;
}
__device__ __forceinline__ unsigned short truncbf(float f) { // round-to-zero (cheap)
  union { float f; unsigned u; } v; v.f = f;
  return (unsigned short)(v.u >> 16);
}

// ---------------------------------------------------------------------------
// K1: partial Gram via MFMA. Gram[g] = X_g^T X_g (bf16 inputs, fp32 acc).
// ---------------------------------------------------------------------------
__global__ __launch_bounds__(256) void gram_mfma_kernel(
    const float* __restrict__ feats, float* __restrict__ partial,
    int L, int KS) {
  const int g = blockIdx.x / KS;
  const int s = blockIdx.x - g * KS;
  const int chunk = L / KS;
  const float* __restrict__ X = feats + ((size_t)g * L + (size_t)s * chunk) * D;

  __shared__ unsigned short sXT[128][40];  // row stride 80 B
  const int tid = threadIdx.x;
  const int wv = tid >> 6, lane = tid & 63, quad = lane >> 4, ln = lane & 15;

  f32x4 acc[2][8];
#pragma unroll
  for (int rt = 0; rt < 2; ++rt)
#pragma unroll
    for (int ct = 0; ct < 8; ++ct) acc[rt][ct] = (f32x4)(0.f);

  for (int k0 = 0; k0 < chunk; k0 += 32) {
    __syncthreads();
    // stage + transpose: 32 k-rows x 128 d. 512 pair-tasks (16 kpairs x 32 d4).
#pragma unroll
    for (int v = 0; v < 2; ++v) {
      int idx = tid + v * 256;
      int k2 = idx & 15, d4 = idx >> 4;
      int k = k2 * 2, dd = d4 * 4;
      float4 r0 = *(const float4*)(X + (size_t)(k0 + k) * D + dd);
      float4 r1 = *(const float4*)(X + (size_t)(k0 + k + 1) * D + dd);
      const float* p0 = (const float*)&r0;
      const float* p1 = (const float*)&r1;
#pragma unroll
      for (int i = 0; i < 4; ++i) {
        unsigned pack = (unsigned)f2bf(p0[i]) | ((unsigned)f2bf(p1[i]) << 16);
        *(unsigned*)&sXT[dd + i][k] = pack;
      }
    }
    __syncthreads();
    bf16x8 af[2], bfr[8];
#pragma unroll
    for (int rt = 0; rt < 2; ++rt)
      af[rt] = *(const bf16x8*)&sXT[32 * wv + 16 * rt + ln][quad * 8];
#pragma unroll
    for (int ct = 0; ct < 8; ++ct)
      bfr[ct] = *(const bf16x8*)&sXT[16 * ct + ln][quad * 8];
#pragma unroll
    for (int rt = 0; rt < 2; ++rt)
#pragma unroll
      for (int ct = 0; ct < 8; ++ct)
        acc[rt][ct] = __builtin_amdgcn_mfma_f32_16x16x32_bf16(
            af[rt], bfr[ct], acc[rt][ct], 0, 0, 0);
  }

  float* P = partial + (size_t)blockIdx.x * (D * D);
#pragma unroll
  for (int rt = 0; rt < 2; ++rt)
#pragma unroll
    for (int ct = 0; ct < 8; ++ct)
#pragma unroll
      for (int r = 0; r < 4; ++r)
        P[(size_t)(32 * wv + 16 * rt + quad * 4 + r) * D + 16 * ct + ln] =
            acc[rt][ct][r];
}

// ---------------------------------------------------------------------------
// K2: reduce KS partials -> bf16 Gram.  grid = GRAPHS*D*D/256.
// ---------------------------------------------------------------------------
__global__ __launch_bounds__(256) void gram_reduce_bf_kernel(
    const float* __restrict__ partial, unsigned short* __restrict__ gram,
    int KS) {
  int idx = blockIdx.x * 256 + threadIdx.x;
  int g = idx >> 14;                 // / (128*128)
  const float* P = partial + (size_t)g * KS * (D * D) + (idx & (D * D - 1));
  float s = 0.f;
  for (int k = 0; k < KS; ++k) s += P[(size_t)k * (D * D)];
  gram[idx] = f2bf(s);
}

// ---------------------------------------------------------------------------
// W2: w2bf[p][d] = bf16(w[p][d]^2).  grid = D*D/256 = 64.
// ---------------------------------------------------------------------------
__global__ __launch_bounds__(256) void w2_kernel(
    const float* __restrict__ w, unsigned short* __restrict__ w2) {
  int idx = blockIdx.x * 256 + threadIdx.x;
  float v = w[idx];
  w2[idx] = f2bf(v * v);
}

// ---------------------------------------------------------------------------
// K3: fused main, MFMA. One block = 32 rows of graph gi; 4 waves split 128 cols.
//  phase1: V2 = A * Gram[gi^1]   (Gram symmetric -> B-frag reads rows directly)
//  phase2: (A.V2, A.A, V2.V2) GEMM vs W2 rows  -> num, n1s, n2s
//  epilogue: out = num / max(sqrt(n1s*n2s), 1e-8)
// ---------------------------------------------------------------------------
__global__ __launch_bounds__(256) void fused_mfma_kernel(
    const float* __restrict__ feats, const unsigned short* __restrict__ gram,
    const unsigned short* __restrict__ w2, float* __restrict__ out, int L) {
  const int tiles = L / 32;
  const int gi = blockIdx.x / tiles;
  const int row0 = (blockIdx.x - gi * tiles) * 32;
  const float* __restrict__ A = feats + ((size_t)gi * L + row0) * D;
  const unsigned short* __restrict__ G = gram + (size_t)(gi ^ 1) * (D * D);
  float* __restrict__ O = out + ((size_t)gi * L + row0) * D;

  __shared__ unsigned short sA[32][136];   // row stride 272 B = 17*16
  __shared__ unsigned short sV[32][136];
  __shared__ unsigned short sB[128][136];  // Gram, then reused for W2

  const int tid = threadIdx.x;
  const int wv = tid >> 6, lane = tid & 63, quad = lane >> 4, ln = lane & 15;

  // stage A (fp32 -> bf16): 1024 float4 tasks, 4/thread
#pragma unroll
  for (int v = 0; v < 4; ++v) {
    int idx = tid + v * 256;
    int r = idx >> 5, c4 = idx & 31;
    float4 t = *(const float4*)(A + (size_t)r * D + c4 * 4);
    unsigned lo = (unsigned)f2bf(t.x) | ((unsigned)f2bf(t.y) << 16);
    unsigned hi = (unsigned)f2bf(t.z) | ((unsigned)f2bf(t.w) << 16);
    *(unsigned*)&sA[r][c4 * 4] = lo;
    *(unsigned*)&sA[r][c4 * 4 + 2] = hi;
  }
  // stage Gram (bf16 copy, 16B chunks): 128 rows x 16 uint4 = 2048 tasks, 8/thread
#pragma unroll
  for (int v = 0; v < 8; ++v) {
    int idx = tid + v * 256;
    int r = idx >> 4, c16 = idx & 15;
    uint4 t = *(const uint4*)(G + (size_t)r * D + c16 * 8);
    *(uint4*)&sB[r][c16 * 8] = t;
  }
  __syncthreads();

  // ---- phase 1: V2 = A * Gram ----
  f32x4 acc[2][2];
#pragma unroll
  for (int rt = 0; rt < 2; ++rt)
#pragma unroll
    for (int ct = 0; ct < 2; ++ct) acc[rt][ct] = (f32x4)(0.f);

#pragma unroll
  for (int kc = 0; kc < 4; ++kc) {
    bf16x8 af[2], bfr[2];
#pragma unroll
    for (int rt = 0; rt < 2; ++rt)
      af[rt] = *(const bf16x8*)&sA[16 * rt + ln][kc * 32 + quad * 8];
#pragma unroll
    for (int ct = 0; ct < 2; ++ct)
      bfr[ct] = *(const bf16x8*)&sB[32 * wv + 16 * ct + ln][kc * 32 + quad * 8];
#pragma unroll
    for (int rt = 0; rt < 2; ++rt)
#pragma unroll
      for (int ct = 0; ct < 2; ++ct)
        acc[rt][ct] = __builtin_amdgcn_mfma_f32_16x16x32_bf16(
            af[rt], bfr[ct], acc[rt][ct], 0, 0, 0);
  }
  // park V2 as bf16 (C-layout -> row-major LDS)
#pragma unroll
  for (int rt = 0; rt < 2; ++rt)
#pragma unroll
    for (int ct = 0; ct < 2; ++ct)
#pragma unroll
      for (int r = 0; r < 4; ++r)
        sV[16 * rt + quad * 4 + r][32 * wv + 16 * ct + ln] = f2bf(acc[rt][ct][r]);
  __syncthreads();  // sV visible; phase-1 reads of sB complete

  // stage W2 into sB: 128 rows x 16 uint4 = 2048 tasks, 8/thread
#pragma unroll
  for (int v = 0; v < 8; ++v) {
    int idx = tid + v * 256;
    int r = idx >> 4, c16 = idx & 15;
    uint4 t = *(const uint4*)(w2 + (size_t)r * D + c16 * 8);
    *(uint4*)&sB[r][c16 * 8] = t;
  }
  __syncthreads();

  // ---- phase 2: three GEMMs vs W2 ----
  f32x4 an[2][2], s1[2][2], s2[2][2];
#pragma unroll
  for (int rt = 0; rt < 2; ++rt)
#pragma unroll
    for (int ct = 0; ct < 2; ++ct) {
      an[rt][ct] = (f32x4)(0.f);
      s1[rt][ct] = (f32x4)(0.f);
      s2[rt][ct] = (f32x4)(0.f);
    }

#pragma unroll
  for (int dc = 0; dc < 4; ++dc) {
    bf16x8 fx2[2], faa[2], fvv[2];
#pragma unroll
    for (int rt = 0; rt < 2; ++rt) {
      bf16x8 xa = *(const bf16x8*)&sA[16 * rt + ln][dc * 32 + quad * 8];
      bf16x8 xv = *(const bf16x8*)&sV[16 * rt + ln][dc * 32 + quad * 8];
#pragma unroll
      for (int j = 0; j < 8; ++j) {
        float a = bf2f((unsigned short)xa[j]);
        float vv = bf2f((unsigned short)xv[j]);
        fx2[rt][j] = (short)truncbf(a * vv);
        faa[rt][j] = (short)truncbf(a * a);
        fvv[rt][j] = (short)truncbf(vv * vv);
      }
    }
    bf16x8 wf[2];
#pragma unroll
    for (int ct = 0; ct < 2; ++ct)
      wf[ct] = *(const bf16x8*)&sB[32 * wv + 16 * ct + ln][dc * 32 + quad * 8];
#pragma unroll
    for (int rt = 0; rt < 2; ++rt)
#pragma unroll
      for (int ct = 0; ct < 2; ++ct) {
        an[rt][ct] = __builtin_amdgcn_mfma_f32_16x16x32_bf16(
            fx2[rt], wf[ct], an[rt][ct], 0, 0, 0);
        s1[rt][ct] = __builtin_amdgcn_mfma_f32_16x16x32_bf16(
            faa[rt], wf[ct], s1[rt][ct], 0, 0, 0);
        s2[rt][ct] = __builtin_amdgcn_mfma_f32_16x16x32_bf16(
            fvv[rt], wf[ct], s2[rt][ct], 0, 0, 0);
      }
  }

  // ---- epilogue ----
#pragma unroll
  for (int rt = 0; rt < 2; ++rt)
#pragma unroll
    for (int ct = 0; ct < 2; ++ct)
#pragma unroll
      for (int r = 0; r < 4; ++r) {
        float num = an[rt][ct][r];
        float den = fmaxf(sqrtf(s1[rt][ct][r] * s2[rt][ct][r]), 1e-8f);
        O[(size_t)(16 * rt + quad * 4 + r) * D + 32 * wv + 16 * ct + ln] =
            num / den;
      }
}

extern "C" void kernel_launch(void* const* d_in, const int* in_sizes, int n_in,
                              void* d_out, int out_size, void* d_ws, size_t ws_size,
                              hipStream_t stream) {
  const float* feats = (const float*)d_in[0];
  const float* w = (const float*)d_in[1];
  float* out = (float*)d_out;
  const int L = (in_sizes[0] / D) / GRAPHS;  // 2048

  const size_t gramF32 = (size_t)GRAPHS * D * D * sizeof(float);      // 4 MiB
  const size_t gramBF = (size_t)GRAPHS * D * D * sizeof(unsigned short);  // 2 MiB
  const size_t w2BF = (size_t)D * D * sizeof(unsigned short);         // 32 KiB
  int KS = 8;
  while (KS > 1 && (size_t)KS * gramF32 + gramBF + w2BF > ws_size) KS >>= 1;

  float* partial = (float*)d_ws;
  unsigned short* gramBuf = (unsigned short*)((char*)d_ws + (size_t)KS * gramF32);
  unsigned short* w2Buf = gramBuf + (size_t)GRAPHS * D * D;

  hipLaunchKernelGGL(w2_kernel, dim3(D * D / 256), dim3(256), 0, stream, w, w2Buf);
  hipLaunchKernelGGL(gram_mfma_kernel, dim3(GRAPHS * KS), dim3(256), 0, stream,
                     feats, partial, L, KS);
  hipLaunchKernelGGL(gram_reduce_bf_kernel, dim3(GRAPHS * D * D / 256), dim3(256),
                     0, stream, partial, gramBuf, KS);
  hipLaunchKernelGGL(fused_mfma_kernel, dim3(GRAPHS * (L / 32)), dim3(256), 0,
                     stream, feats, gramBuf, w2Buf, out, L);
}